// Round 8
// baseline (235.340 us; speedup 1.0000x reference)
//
#include <hip/hip_runtime.h>
#include <stdint.h>

// ---------- types / helpers ----------
typedef __attribute__((ext_vector_type(8))) short   short8;   // 8 bf16 (4 VGPRs)
typedef __attribute__((ext_vector_type(8))) __bf16  bf16x8;
typedef __attribute__((ext_vector_type(4))) float   floatx4;

__device__ __forceinline__ float bf2f(uint16_t h) {
    union { uint32_t u; float f; } v; v.u = ((uint32_t)h) << 16; return v.f;
}
__device__ __forceinline__ uint16_t f2bf(float f) {
    union { float f; uint32_t u; } v; v.f = f;
    uint32_t u = v.u;
    u += 0x7FFFu + ((u >> 16) & 1u);   // RNE
    return (uint16_t)(u >> 16);
}
__device__ __forceinline__ floatx4 mfma16(short8 a, short8 b, floatx4 c) {
    return __builtin_amdgcn_mfma_f32_16x16x32_bf16(
        __builtin_bit_cast(bf16x8, a), __builtin_bit_cast(bf16x8, b), c, 0, 0, 0);
}
// async global->LDS, 16B per lane
__device__ __forceinline__ void gll16(const short* g, short* l) {
    __builtin_amdgcn_global_load_lds(
        (const __attribute__((address_space(1))) uint32_t*)g,
        (__attribute__((address_space(3))) uint32_t*)l, 16, 0, 0);
}
// XOR bank swizzle: physical 16B-group = logical group ^ (row & 7).
// Applied to the GLOBAL source column during staging and to the group index
// on LDS reads. Kills the 128B-row-stride 16-way conflict. [R12: 1.94e7->5e5]

// ---------- merged f32->bf16 conversion (x, 4 weights, 4 biases, er^T) ----------
__global__ void conv_all(
    const float* __restrict__ x,
    const float* __restrict__ Wq, const float* __restrict__ Wk,
    const float* __restrict__ Wv, const float* __restrict__ Wo,
    const float* __restrict__ bq, const float* __restrict__ bk,
    const float* __restrict__ bv, const float* __restrict__ bo,
    const float* __restrict__ er,
    short* __restrict__ xb, short* __restrict__ Wb,
    short* __restrict__ ball, short* __restrict__ ErT)
{
    int blk = blockIdx.x, tid = threadIdx.x;
    if (blk < 4096) {                            // x: 1M float4
        int i = blk * 256 + tid;
        float4 v = ((const float4*)x)[i];
        ((short4*)xb)[i] = make_short4((short)f2bf(v.x), (short)f2bf(v.y),
                                       (short)f2bf(v.z), (short)f2bf(v.w));
    } else if (blk < 8192) {                     // weights: 4 x 256K float4
        int rel = blk - 4096;
        int wsel = rel >> 10;
        int i = (rel & 1023) * 256 + tid;
        const float* W = (wsel == 0) ? Wq : (wsel == 1) ? Wk : (wsel == 2) ? Wv : Wo;
        float4 v = ((const float4*)W)[i];
        ((short4*)(Wb + ((size_t)wsel << 20)))[i] =
            make_short4((short)f2bf(v.x), (short)f2bf(v.y),
                        (short)f2bf(v.z), (short)f2bf(v.w));
    } else if (blk < 8448) {                     // er[64][1024] -> ErT[1024][64]
        int idx = (blk - 8192) * 256 + tid;
        int w = idx >> 6, d = idx & 63;
        ErT[idx] = (short)f2bf(er[d * 1024 + w]);
    } else {                                     // biases: 4 x 1024
        int idx = (blk - 8448) * 256 + tid;
        int sel = idx >> 10, j = idx & 1023;
        const float* s = (sel == 0) ? bq : (sel == 1) ? bk : (sel == 2) ? bv : bo;
        ball[idx] = (short)f2bf(s[j]);
    }
}

// ---------- shared 2ph GEMM machinery ----------
#define VM0  asm volatile("s_waitcnt vmcnt(0)" ::: "memory")
#define BARR asm volatile("s_barrier" ::: "memory")

// stage one 64x64 subtile (row-major src, ld=1024) into an 8KB LDS region
__device__ __forceinline__ void stage_unit(const short* src, short* region, int tid)
{
    const int row  = tid >> 3;                       // 0..63
    const int scol = (((tid & 7) ^ (row & 7)) << 3); // swizzled source col (shorts)
    gll16(src + (size_t)row * 1024 + scol, region + tid * 8);
}

// ---------- fused QKV GEMM: 256x192, BK=64, 2ph, L2-GROUPED XCD swizzle ----------
// (unchanged from R7)
#define SAU(buf, u) (As + (buf) * 16384 + (u) * 4096)
#define SBU(buf, u) (Bs + (buf) * 12288 + (u) * 4096)
#define STG_A(buf, u, kt) stage_unit(Asrc + (size_t)(u) * 65536 + (size_t)(kt) * 64, SAU(buf, u), tid)
#define STG_B(buf, u, kt) stage_unit(Bsrc + (size_t)(u) * 65536 + (size_t)(kt) * 64, SBU(buf, u), tid)
#define STG7(buf, kt) do { \
    STG_A(buf, 0, kt); STG_A(buf, 1, kt); STG_A(buf, 2, kt); STG_A(buf, 3, kt); \
    STG_B(buf, 0, kt); STG_B(buf, 1, kt); STG_B(buf, 2, kt); } while (0)

#define RD_A(buf) do { \
    _Pragma("unroll") for (int fr_ = 0; fr_ < 8; ++fr_) { \
        const short* p_ = SAU(buf, wm * 2 + (fr_ >> 2)) + ((fr_ & 3) * 16 + lrow) * 64; \
        _Pragma("unroll") for (int ks_ = 0; ks_ < 2; ++ks_) \
            a[fr_][ks_] = *(const short8*)&p_[((ks_ * 4 + quad) ^ rx) << 3]; \
    } } while (0)

// fragment fc reads ONLY unit fc; wave wn owns rows wn*16..wn*16+15 of that unit
#define RD_B(buf, c) do { \
    const short* p_ = SBU(buf, c) + (wn * 16 + lrow) * 64; \
    _Pragma("unroll") for (int ks_ = 0; ks_ < 2; ++ks_) \
        bb[ks_] = *(const short8*)&p_[((ks_ * 4 + quad) ^ rx) << 3]; \
    } while (0)

#define MFMA_PH(c) do { \
    __builtin_amdgcn_s_setprio(1); \
    _Pragma("unroll") for (int ks_ = 0; ks_ < 2; ++ks_) \
        _Pragma("unroll") for (int fr_ = 0; fr_ < 8; ++fr_) \
            acc[fr_][c] = mfma16(a[fr_][ks_], bb[ks_], acc[fr_][c]); \
    __builtin_amdgcn_s_setprio(0); \
    } while (0)

__global__ __launch_bounds__(512, 2) void qkv_gemm2ph(
    const short* __restrict__ x, const short* __restrict__ Wb,
    const short* __restrict__ ball,
    short* __restrict__ Qb, short* __restrict__ Kb, short* __restrict__ Vb)
{
    extern __shared__ short lds[];
    short* As = lds;              // 2 buf x 4 units x 4096 shorts = 64 KiB
    short* Bs = lds + 32768;      // 2 buf x 3 units x 4096 shorts = 48 KiB
    const int tid  = threadIdx.x;
    const int wid  = tid >> 6;
    const int lane = tid & 63;
    const int wm   = wid >> 2;          // 0..1  (M warp)
    const int wn   = wid & 3;           // 0..3  (N warp)
    const int lrow = lane & 15;
    const int quad = lane >> 4;
    const int rx   = lrow & 7;
    const int bid  = blockIdx.x;
    const int xcd  = bid & 7, gg = bid >> 3;
    const int mi   = (xcd >> 1) * 4 + (gg & 3);      // 0..15
    const int ni   = (xcd & 1) * 8 + (gg >> 2);      // 0..15
    const int m0   = mi * 256, n0 = ni * 192;
    const short* Asrc = x  + (size_t)m0 * 1024;
    const short* Bsrc = Wb + (size_t)n0 * 1024;

    floatx4 acc[8][3];
#pragma unroll
    for (int r = 0; r < 8; ++r)
#pragma unroll
        for (int c = 0; c < 3; ++c) acc[r][c] = (floatx4){0.f, 0.f, 0.f, 0.f};

    short8 a[8][2], bb[2];

    // prologue: buf0 <- tile 0
    STG7(0, 0);
    VM0; BARR;

#pragma unroll 2
    for (int t = 0; t < 16; ++t) {
        const int cur = t & 1;
        if (t < 15) STG7(cur ^ 1, t + 1);   // issue next tile's 7 units first
        RD_A(cur);
        RD_B(cur, 0); MFMA_PH(0);
        RD_B(cur, 1); MFMA_PH(1);
        RD_B(cur, 2); MFMA_PH(2);
        VM0; BARR;                           // next buf landed + all reads done
    }

    // epilogue: bias add + layout-specific bf16 store
#pragma unroll
    for (int fc = 0; fc < 3; ++fc) {
        int col = n0 + fc * 64 + wn * 16 + lrow;     // 0..3071
        int z   = col >> 10;                          // 0=Q 1=K 2=V
        int c1  = col & 1023;
        short* dst = (z == 0) ? Qb : (z == 1) ? Kb : Vb;
        float bv = bf2f((uint16_t)ball[col]);
#pragma unroll
        for (int fr = 0; fr < 8; ++fr) {
#pragma unroll
            for (int g = 0; g < 4; ++g) {
                int m = m0 + wm * 128 + fr * 16 + quad * 4 + g;
                float fv = acc[fr][fc][g] + bv;
                int bh = (m >> 10) * 16 + (c1 >> 6);
                if (z == 2)   // V^T: [b,h,d=64,w=1024]
                    dst[(size_t)bh * 65536 + (size_t)(c1 & 63) * 1024 + (m & 1023)] =
                        (short)f2bf(fv);
                else          // Q/K: [b,h,w=1024,d=64]
                    dst[(size_t)bh * 65536 + (size_t)(m & 1023) * 64 + (c1 & 63)] =
                        (short)f2bf(fv);
            }
        }
    }
}

// ---------- out GEMM: 128x128, BK=64, 2ph clone (unchanged from R7) ----------
#define SAU2(buf, u) (As2 + (buf) * 8192 + (u) * 4096)
#define SBU2(buf, u) (Bs2 + (buf) * 8192 + (u) * 4096)
#define STG4(buf, kt) do { \
    stage_unit(Asrc + 0 * 65536 + (size_t)(kt) * 64, SAU2(buf, 0), tid); \
    stage_unit(Asrc + 1 * 65536 + (size_t)(kt) * 64, SAU2(buf, 1), tid); \
    stage_unit(Bsrc + 0 * 65536 + (size_t)(kt) * 64, SBU2(buf, 0), tid); \
    stage_unit(Bsrc + 1 * 65536 + (size_t)(kt) * 64, SBU2(buf, 1), tid); } while (0)

#define RD_A2(buf) do { \
    _Pragma("unroll") for (int fr_ = 0; fr_ < 4; ++fr_) { \
        const short* p_ = SAU2(buf, wm) + (fr_ * 16 + lrow) * 64; \
        _Pragma("unroll") for (int ks_ = 0; ks_ < 2; ++ks_) \
            a[fr_][ks_] = *(const short8*)&p_[((ks_ * 4 + quad) ^ rx) << 3]; \
    } } while (0)

#define RD_B2(buf, c) do { \
    const short* p_ = SBU2(buf, c) + (wn * 16 + lrow) * 64; \
    _Pragma("unroll") for (int ks_ = 0; ks_ < 2; ++ks_) \
        bb[ks_] = *(const short8*)&p_[((ks_ * 4 + quad) ^ rx) << 3]; \
    } while (0)

#define MFMA_PH2(c) do { \
    __builtin_amdgcn_s_setprio(1); \
    _Pragma("unroll") for (int ks_ = 0; ks_ < 2; ++ks_) \
        _Pragma("unroll") for (int fr_ = 0; fr_ < 4; ++fr_) \
            acc[fr_][c] = mfma16(a[fr_][ks_], bb[ks_], acc[fr_][c]); \
    __builtin_amdgcn_s_setprio(0); \
    } while (0)

__global__ __launch_bounds__(512, 2) void out_gemm2ph(
    const short* __restrict__ AV, const short* __restrict__ Wo,
    const short* __restrict__ bo, float* __restrict__ out)
{
    __shared__ short As2[2 * 2 * 4096];   // 32 KiB
    __shared__ short Bs2[2 * 2 * 4096];   // 32 KiB
    const int tid  = threadIdx.x;
    const int wid  = tid >> 6;
    const int lane = tid & 63;
    const int wm   = wid >> 2;
    const int wn   = wid & 3;
    const int lrow = lane & 15;
    const int quad = lane >> 4;
    const int rx   = lrow & 7;
    const int bid  = blockIdx.x + blockIdx.y * 32;
    const int xcd  = bid & 7, gg = bid >> 3;
    const int mi   = (xcd & 3) * 8 + (gg & 7);       // 0..31
    const int ni   = (xcd >> 2) * 4 + (gg >> 3);     // 0..7
    const int m0   = mi * 128, n0 = ni * 128;
    const short* Asrc = AV + (size_t)m0 * 1024;
    const short* Bsrc = Wo + (size_t)n0 * 1024;

    floatx4 acc[4][2];
#pragma unroll
    for (int r = 0; r < 4; ++r)
#pragma unroll
        for (int c = 0; c < 2; ++c) acc[r][c] = (floatx4){0.f, 0.f, 0.f, 0.f};

    short8 a[4][2], bb[2];

    STG4(0, 0);
    VM0; BARR;

#pragma unroll 2
    for (int t = 0; t < 16; ++t) {
        const int cur = t & 1;
        if (t < 15) STG4(cur ^ 1, t + 1);
        RD_A2(cur);
        RD_B2(cur, 0); MFMA_PH2(0);
        RD_B2(cur, 1); MFMA_PH2(1);
        VM0; BARR;
    }

#pragma unroll
    for (int fc = 0; fc < 2; ++fc) {
        int col = n0 + fc * 64 + wn * 16 + lrow;
        float bv = bf2f((uint16_t)bo[col]);
#pragma unroll
        for (int fr = 0; fr < 4; ++fr) {
#pragma unroll
            for (int g = 0; g < 4; ++g) {
                int m = m0 + wm * 64 + fr * 16 + quad * 4 + g;
                out[(size_t)m * 1024 + col] = acc[fr][fc][g] + bv;
            }
        }
    }
}

// ---------- flash attention v3: 64-row blocks, Q-direct, 3 blocks/CU ----------
// R8: attn was dependency-chain-bound (Mfma 19.5 / VALU 47 / LDS ~40 / HBM 5.5 —
// nothing saturated) at 16 waves/CU (66KB LDS -> 2 blocks/CU; grid 512 also caps
// at 2/CU). Fix: (1) i0-tiles 128->64 (grid 1024), wave = 16 rows x 32 j;
// (2) e-term B-frags (kk>=2) read Q DIRECT from global/L2 (4x16B/wave/jt,
// issued early) -> Qks staging eliminated; (3) LDS 66->41KB (Ks16+Vs16+Ps9)
// -> 3 blocks/CU; __launch_bounds__(512,6) pins VGPR<=85 so 24 waves fit.
#define PSTR 72   // Ps row stride (shorts): 16B-aligned, non-pow2 banks
__global__ __launch_bounds__(512, 6) void attn_kernel(
    const short* __restrict__ Q, const short* __restrict__ K,
    const short* __restrict__ Vt, const short* __restrict__ ErT,
    short* __restrict__ AV)
{
    __shared__ short smem[20992];            // 41 KiB flat
    short* Ks  = smem;                       // [2][4096]
    short* Vs  = smem + 8192;                // [2][4096]
    short* Ps  = smem + 16384;               // [64*PSTR] = 4608 shorts
    float* oaccS = (float*)smem;             // [64][65] f32 end-combine scratch
    float* lrunS = ((float*)smem) + 64 * 65; // 64 f32
    // scratch = 16896B = 8448 shorts: covers Ks (both buffers) + first 256
    // shorts of Vs[0]. Vs[0] last read at jt=14's PV, Ks[1] at jt=15 — all
    // before the post-loop __syncthreads that precedes any scratch write.

    const int tid  = threadIdx.x;
    const int wid  = tid >> 6;
    const int lane = tid & 63;
    const int rg   = wid >> 1;          // 0..3: row-group (16 q-rows)
    const int cg   = wid & 1;           // 0..1: col-group (32 j's)
    const int lrow = lane & 15;
    const int quad = lane >> 4;
    const int lk   = quad * 8;
    const int srow = lane >> 3;
    const int sscol = (((lane & 7) ^ (srow & 7)) << 3);
    const int rx = lrow & 7;
    const int h = blockIdx.x, b = blockIdx.y;
    const int bh = b * 16 + h;
    const int i0 = blockIdx.z * 64;
    const short* Qbh = Q  + (size_t)bh * 65536;
    const short* Kbh = K  + (size_t)bh * 65536;
    const short* Vbh = Vt + (size_t)bh * 65536;

    // Qaug A-frag: 16 rows x full K=128 ([Q | ErT])
    short8 qa[4];
    {
        int row = i0 + rg * 16 + lrow;
#pragma unroll
        for (int kk = 0; kk < 2; ++kk) {
            qa[kk]     = *(const short8*)&Qbh[(size_t)row * 64 + kk * 32 + lk];
            qa[kk + 2] = *(const short8*)&ErT[(size_t)row * 64 + kk * 32 + lk];
        }
    }

    float lrun[4];
    floatx4 oacc[4];
#pragma unroll
    for (int g = 0; g < 4; ++g) lrun[g] = 0.f;
#pragma unroll
    for (int c = 0; c < 4; ++c) oacc[c] = (floatx4){0.f, 0.f, 0.f, 0.f};

    // prologue: stage jt=0 into buffer 0 (wave wid stages chunk wid)
    gll16(Kbh + (size_t)(wid * 8 + srow) * 64 + sscol,    Ks + wid * 512 + lane * 8);
    gll16(Vbh + (size_t)(wid * 8 + srow) * 1024 + sscol,  Vs + wid * 512 + lane * 8);

    const float sc2 = 1.44269504088896f / 32.0f;   // log2(e)/sqrt(c)

    for (int jt = 0; jt < 16; ++jt) {
        const int cur = jt & 1;
        __syncthreads();   // buf[cur] staged (vmcnt(0) drained) + reads done

        if (jt < 15) {     // prefetch jt+1 into buf[cur^1]
            int j1 = (jt + 1) * 64;
            gll16(Kbh + (size_t)(j1 + wid * 8 + srow) * 64 + sscol,    Ks + (cur ^ 1) * 4096 + wid * 512 + lane * 8);
            gll16(Vbh + (size_t)(wid * 8 + srow) * 1024 + j1 + sscol,  Vs + (cur ^ 1) * 4096 + wid * 512 + lane * 8);
        }

        // Q-direct B-frags for the e-term (kk=2,3) — issue early, L2-resident
        short8 qj[2][2];
#pragma unroll
        for (int kl = 0; kl < 2; ++kl)
#pragma unroll
            for (int c = 0; c < 2; ++c)
                qj[kl][c] = *(const short8*)&Qbh[
                    (size_t)(jt * 64 + cg * 32 + c * 16 + lrow) * 64 + kl * 32 + lk];

        // S-MFMA: rows rg*16..+15 x cols (j) cg*32..+31
        floatx4 s[2];
#pragma unroll
        for (int c = 0; c < 2; ++c) s[c] = (floatx4){0.f, 0.f, 0.f, 0.f};
#pragma unroll
        for (int kk = 0; kk < 2; ++kk) {    // K-part from LDS
            short8 kb[2];
#pragma unroll
            for (int c = 0; c < 2; ++c)
                kb[c] = *(const short8*)&Ks[cur * 4096 +
                                            (cg * 32 + c * 16 + lrow) * 64 +
                                            (((kk * 4 + quad) ^ rx) << 3)];
#pragma unroll
            for (int c = 0; c < 2; ++c)
                s[c] = mfma16(qa[kk], kb[c], s[c]);
        }
#pragma unroll
        for (int kl = 0; kl < 2; ++kl)      // e-term with Q-direct frags
#pragma unroll
            for (int c = 0; c < 2; ++c)
                s[c] = mfma16(qa[kl + 2], qj[kl][c], s[c]);

        // no-max softmax: p = exp2(s*sc2); per-lane partial row sums (deferred)
#pragma unroll
        for (int c = 0; c < 2; ++c)
#pragma unroll
            for (int g = 0; g < 4; ++g)
                s[c][g] = exp2f(s[c][g] * sc2);
#pragma unroll
        for (int g = 0; g < 4; ++g)
            lrun[g] += s[0][g] + s[1][g];

        // write P to wave-private 16x32 block of Ps
#pragma unroll
        for (int c = 0; c < 2; ++c)
#pragma unroll
            for (int g = 0; g < 4; ++g)
                Ps[(rg * 16 + quad * 4 + g) * PSTR + cg * 32 + c * 16 + lrow] =
                    (short)f2bf(s[c][g]);
        __asm__ __volatile__("" ::: "memory");

        // PV-MFMA: k = wave's 32 j's (single K=32 step)
        {
            short8 pa, vb[4];
            pa = *(const short8*)&Ps[(rg * 16 + lrow) * PSTR + cg * 32 + lk];
#pragma unroll
            for (int c = 0; c < 4; ++c)
                vb[c] = *(const short8*)&Vs[cur * 4096 + (c * 16 + lrow) * 64 +
                                            (((cg * 4 + quad) ^ rx) << 3)];
#pragma unroll
            for (int c = 0; c < 4; ++c)
                oacc[c] = mfma16(pa, vb[c], oacc[c]);
        }
    }

    // ---- end-combine across the 2 col-groups ----
#pragma unroll
    for (int g = 0; g < 4; ++g) {
        float r = lrun[g];
#pragma unroll
        for (int d = 1; d < 16; d <<= 1) r += __shfl_xor(r, d, 64);
        lrun[g] = r;
    }

    __syncthreads();   // all LDS reads of the jt loop complete
    if (cg == 0) {
#pragma unroll
        for (int c = 0; c < 4; ++c)
#pragma unroll
            for (int g = 0; g < 4; ++g)
                oaccS[(rg * 16 + quad * 4 + g) * 65 + c * 16 + lrow] = oacc[c][g];
        if (lrow == 0)
#pragma unroll
            for (int g = 0; g < 4; ++g)
                lrunS[rg * 16 + quad * 4 + g] = lrun[g];
    }
    __syncthreads();
    if (cg == 1) {
#pragma unroll
        for (int g = 0; g < 4; ++g) {
            int row = rg * 16 + quad * 4 + g;
            float lt = lrun[g] + lrunS[row];
#pragma unroll
            for (int c = 0; c < 4; ++c) {
                float tot = oacc[c][g] + oaccS[row * 65 + c * 16 + lrow];
                AV[((size_t)b * 1024 + i0 + row) * 1024 + h * 64 + c * 16 + lrow] =
                    (short)f2bf(tot / lt);
            }
        }
    }
}

// ---------- launcher ----------
extern "C" void kernel_launch(void* const* d_in, const int* in_sizes, int n_in,
                              void* d_out, int out_size, void* d_ws, size_t ws_size,
                              hipStream_t stream) {
    const float* x  = (const float*)d_in[0];
    const float* Wq = (const float*)d_in[1];
    const float* bq = (const float*)d_in[2];
    const float* Wk = (const float*)d_in[3];
    const float* bk = (const float*)d_in[4];
    const float* Wv = (const float*)d_in[5];
    const float* bv = (const float*)d_in[6];
    const float* Wo = (const float*)d_in[7];
    const float* bo = (const float*)d_in[8];
    const float* er = (const float*)d_in[9];
    float* out = (float*)d_out;

    const size_t M1 = 1u << 20;
    short* ws   = (short*)d_ws;
    short* xb   = (short*)d_out;      // bf16 x in d_out's first 8MB; dead before out_gemm
    short* Qb   = ws;                 // 4M  [b,h,w,d]
    short* Kb   = ws + 4 * M1;        // 4M  [b,h,w,d]
    short* Vb   = ws + 8 * M1;        // 4M  [b,h,d,w]
    short* AVb  = ws + 12 * M1;       // 4M  [b,w,c]
    short* Wb   = ws + 16 * M1;       // 4M  (Wq|Wk|Wv|Wo bf16, contiguous)
    short* ball = ws + 20 * M1;       // 4x1024 (bq,bk,bv,bo)
    short* ErT  = ws + 20 * M1 + 4096; // 65536 [w,d]

    static bool attr_done = false;
    if (!attr_done) {
        hipFuncSetAttribute((const void*)qkv_gemm2ph,
                            hipFuncAttributeMaxDynamicSharedMemorySize, 114688);
        attr_done = true;
    }

    hipLaunchKernelGGL(conv_all, dim3(8464), dim3(256), 0, stream,
                       x, Wq, Wk, Wv, Wo, bq, bk, bv, bo, er, xb, Wb, ball, ErT);
    hipLaunchKernelGGL(qkv_gemm2ph, dim3(256), dim3(512), 114688, stream,
                       xb, Wb, ball, Qb, Kb, Vb);
    hipLaunchKernelGGL(attn_kernel, dim3(16, 4, 16), dim3(512), 0, stream,
                       Qb, Kb, Vb, ErT, AVb);
    hipLaunchKernelGGL(out_gemm2ph, dim3(32, 8), dim3(512), 0, stream,
                       AVb, Wb + 3 * M1, ball + 3072, out);
}

// Round 9
// 192.705 us; speedup vs baseline: 1.2212x; 1.2212x over previous
//
#include <hip/hip_runtime.h>
#include <stdint.h>

// ---------- types / helpers ----------
typedef __attribute__((ext_vector_type(8))) short   short8;   // 8 bf16 (4 VGPRs)
typedef __attribute__((ext_vector_type(8))) __bf16  bf16x8;
typedef __attribute__((ext_vector_type(4))) float   floatx4;

__device__ __forceinline__ float bf2f(uint16_t h) {
    union { uint32_t u; float f; } v; v.u = ((uint32_t)h) << 16; return v.f;
}
__device__ __forceinline__ uint16_t f2bf(float f) {
    union { float f; uint32_t u; } v; v.f = f;
    uint32_t u = v.u;
    u += 0x7FFFu + ((u >> 16) & 1u);   // RNE
    return (uint16_t)(u >> 16);
}
// HW packed f32->bf16 (RNE), 2 values per instruction [T12 primitive]
__device__ __forceinline__ uint32_t pk2bf(float lo, float hi) {
    uint32_t r;
    asm volatile("v_cvt_pk_bf16_f32 %0, %1, %2" : "=v"(r) : "v"(lo), "v"(hi));
    return r;
}
__device__ __forceinline__ floatx4 mfma16(short8 a, short8 b, floatx4 c) {
    return __builtin_amdgcn_mfma_f32_16x16x32_bf16(
        __builtin_bit_cast(bf16x8, a), __builtin_bit_cast(bf16x8, b), c, 0, 0, 0);
}
// async global->LDS, 16B per lane
__device__ __forceinline__ void gll16(const short* g, short* l) {
    __builtin_amdgcn_global_load_lds(
        (const __attribute__((address_space(1))) uint32_t*)g,
        (__attribute__((address_space(3))) uint32_t*)l, 16, 0, 0);
}
// XOR bank swizzle: physical 16B-group = logical group ^ (row & 7).
// Applied to the GLOBAL source column during staging and to the group index
// on LDS reads. Kills the 128B-row-stride 16-way conflict. [R12: 1.94e7->5e5]

// ---------- merged f32->bf16 conversion (x, 4 weights, 4 biases, er^T) ----------
__global__ void conv_all(
    const float* __restrict__ x,
    const float* __restrict__ Wq, const float* __restrict__ Wk,
    const float* __restrict__ Wv, const float* __restrict__ Wo,
    const float* __restrict__ bq, const float* __restrict__ bk,
    const float* __restrict__ bv, const float* __restrict__ bo,
    const float* __restrict__ er,
    short* __restrict__ xb, short* __restrict__ Wb,
    short* __restrict__ ball, short* __restrict__ ErT)
{
    int blk = blockIdx.x, tid = threadIdx.x;
    if (blk < 4096) {                            // x: 1M float4
        int i = blk * 256 + tid;
        float4 v = ((const float4*)x)[i];
        ((short4*)xb)[i] = make_short4((short)f2bf(v.x), (short)f2bf(v.y),
                                       (short)f2bf(v.z), (short)f2bf(v.w));
    } else if (blk < 8192) {                     // weights: 4 x 256K float4
        int rel = blk - 4096;
        int wsel = rel >> 10;
        int i = (rel & 1023) * 256 + tid;
        const float* W = (wsel == 0) ? Wq : (wsel == 1) ? Wk : (wsel == 2) ? Wv : Wo;
        float4 v = ((const float4*)W)[i];
        ((short4*)(Wb + ((size_t)wsel << 20)))[i] =
            make_short4((short)f2bf(v.x), (short)f2bf(v.y),
                        (short)f2bf(v.z), (short)f2bf(v.w));
    } else if (blk < 8448) {                     // er[64][1024] -> ErT[1024][64]
        int idx = (blk - 8192) * 256 + tid;
        int w = idx >> 6, d = idx & 63;
        ErT[idx] = (short)f2bf(er[d * 1024 + w]);
    } else {                                     // biases: 4 x 1024
        int idx = (blk - 8448) * 256 + tid;
        int sel = idx >> 10, j = idx & 1023;
        const float* s = (sel == 0) ? bq : (sel == 1) ? bk : (sel == 2) ? bv : bo;
        ball[idx] = (short)f2bf(s[j]);
    }
}

// ---------- shared 2ph GEMM machinery ----------
#define VM0  asm volatile("s_waitcnt vmcnt(0)" ::: "memory")
#define BARR asm volatile("s_barrier" ::: "memory")

// stage one 64x64 subtile (row-major src, ld=1024) into an 8KB LDS region
__device__ __forceinline__ void stage_unit(const short* src, short* region, int tid)
{
    const int row  = tid >> 3;                       // 0..63
    const int scol = (((tid & 7) ^ (row & 7)) << 3); // swizzled source col (shorts)
    gll16(src + (size_t)row * 1024 + scol, region + tid * 8);
}

// ---------- fused QKV GEMM: 256x192, BK=64, 2ph, L2-GROUPED XCD swizzle ----------
// (unchanged from R7)
#define SAU(buf, u) (As + (buf) * 16384 + (u) * 4096)
#define SBU(buf, u) (Bs + (buf) * 12288 + (u) * 4096)
#define STG_A(buf, u, kt) stage_unit(Asrc + (size_t)(u) * 65536 + (size_t)(kt) * 64, SAU(buf, u), tid)
#define STG_B(buf, u, kt) stage_unit(Bsrc + (size_t)(u) * 65536 + (size_t)(kt) * 64, SBU(buf, u), tid)
#define STG7(buf, kt) do { \
    STG_A(buf, 0, kt); STG_A(buf, 1, kt); STG_A(buf, 2, kt); STG_A(buf, 3, kt); \
    STG_B(buf, 0, kt); STG_B(buf, 1, kt); STG_B(buf, 2, kt); } while (0)

#define RD_A(buf) do { \
    _Pragma("unroll") for (int fr_ = 0; fr_ < 8; ++fr_) { \
        const short* p_ = SAU(buf, wm * 2 + (fr_ >> 2)) + ((fr_ & 3) * 16 + lrow) * 64; \
        _Pragma("unroll") for (int ks_ = 0; ks_ < 2; ++ks_) \
            a[fr_][ks_] = *(const short8*)&p_[((ks_ * 4 + quad) ^ rx) << 3]; \
    } } while (0)

// fragment fc reads ONLY unit fc; wave wn owns rows wn*16..wn*16+15 of that unit
#define RD_B(buf, c) do { \
    const short* p_ = SBU(buf, c) + (wn * 16 + lrow) * 64; \
    _Pragma("unroll") for (int ks_ = 0; ks_ < 2; ++ks_) \
        bb[ks_] = *(const short8*)&p_[((ks_ * 4 + quad) ^ rx) << 3]; \
    } while (0)

#define MFMA_PH(c) do { \
    __builtin_amdgcn_s_setprio(1); \
    _Pragma("unroll") for (int ks_ = 0; ks_ < 2; ++ks_) \
        _Pragma("unroll") for (int fr_ = 0; fr_ < 8; ++fr_) \
            acc[fr_][c] = mfma16(a[fr_][ks_], bb[ks_], acc[fr_][c]); \
    __builtin_amdgcn_s_setprio(0); \
    } while (0)

__global__ __launch_bounds__(512, 2) void qkv_gemm2ph(
    const short* __restrict__ x, const short* __restrict__ Wb,
    const short* __restrict__ ball,
    short* __restrict__ Qb, short* __restrict__ Kb, short* __restrict__ Vb)
{
    extern __shared__ short lds[];
    short* As = lds;              // 2 buf x 4 units x 4096 shorts = 64 KiB
    short* Bs = lds + 32768;      // 2 buf x 3 units x 4096 shorts = 48 KiB
    const int tid  = threadIdx.x;
    const int wid  = tid >> 6;
    const int lane = tid & 63;
    const int wm   = wid >> 2;          // 0..1  (M warp)
    const int wn   = wid & 3;           // 0..3  (N warp)
    const int lrow = lane & 15;
    const int quad = lane >> 4;
    const int rx   = lrow & 7;
    const int bid  = blockIdx.x;
    const int xcd  = bid & 7, gg = bid >> 3;
    const int mi   = (xcd >> 1) * 4 + (gg & 3);      // 0..15
    const int ni   = (xcd & 1) * 8 + (gg >> 2);      // 0..15
    const int m0   = mi * 256, n0 = ni * 192;
    const short* Asrc = x  + (size_t)m0 * 1024;
    const short* Bsrc = Wb + (size_t)n0 * 1024;

    floatx4 acc[8][3];
#pragma unroll
    for (int r = 0; r < 8; ++r)
#pragma unroll
        for (int c = 0; c < 3; ++c) acc[r][c] = (floatx4){0.f, 0.f, 0.f, 0.f};

    short8 a[8][2], bb[2];

    // prologue: buf0 <- tile 0
    STG7(0, 0);
    VM0; BARR;

#pragma unroll 2
    for (int t = 0; t < 16; ++t) {
        const int cur = t & 1;
        if (t < 15) STG7(cur ^ 1, t + 1);   // issue next tile's 7 units first
        RD_A(cur);
        RD_B(cur, 0); MFMA_PH(0);
        RD_B(cur, 1); MFMA_PH(1);
        RD_B(cur, 2); MFMA_PH(2);
        VM0; BARR;                           // next buf landed + all reads done
    }

    // epilogue: bias add + layout-specific bf16 store
#pragma unroll
    for (int fc = 0; fc < 3; ++fc) {
        int col = n0 + fc * 64 + wn * 16 + lrow;     // 0..3071
        int z   = col >> 10;                          // 0=Q 1=K 2=V
        int c1  = col & 1023;
        short* dst = (z == 0) ? Qb : (z == 1) ? Kb : Vb;
        float bv = bf2f((uint16_t)ball[col]);
#pragma unroll
        for (int fr = 0; fr < 8; ++fr) {
#pragma unroll
            for (int g = 0; g < 4; ++g) {
                int m = m0 + wm * 128 + fr * 16 + quad * 4 + g;
                float fv = acc[fr][fc][g] + bv;
                int bh = (m >> 10) * 16 + (c1 >> 6);
                if (z == 2)   // V^T: [b,h,d=64,w=1024]
                    dst[(size_t)bh * 65536 + (size_t)(c1 & 63) * 1024 + (m & 1023)] =
                        (short)f2bf(fv);
                else          // Q/K: [b,h,w=1024,d=64]
                    dst[(size_t)bh * 65536 + (size_t)(m & 1023) * 64 + (c1 & 63)] =
                        (short)f2bf(fv);
            }
        }
    }
}

// ---------- out GEMM: 128x128, BK=64, 2ph clone (unchanged from R7) ----------
#define SAU2(buf, u) (As2 + (buf) * 8192 + (u) * 4096)
#define SBU2(buf, u) (Bs2 + (buf) * 8192 + (u) * 4096)
#define STG4(buf, kt) do { \
    stage_unit(Asrc + 0 * 65536 + (size_t)(kt) * 64, SAU2(buf, 0), tid); \
    stage_unit(Asrc + 1 * 65536 + (size_t)(kt) * 64, SAU2(buf, 1), tid); \
    stage_unit(Bsrc + 0 * 65536 + (size_t)(kt) * 64, SBU2(buf, 0), tid); \
    stage_unit(Bsrc + 1 * 65536 + (size_t)(kt) * 64, SBU2(buf, 1), tid); } while (0)

#define RD_A2(buf) do { \
    _Pragma("unroll") for (int fr_ = 0; fr_ < 4; ++fr_) { \
        const short* p_ = SAU2(buf, wm) + (fr_ * 16 + lrow) * 64; \
        _Pragma("unroll") for (int ks_ = 0; ks_ < 2; ++ks_) \
            a[fr_][ks_] = *(const short8*)&p_[((ks_ * 4 + quad) ^ rx) << 3]; \
    } } while (0)

#define RD_B2(buf, c) do { \
    const short* p_ = SBU2(buf, c) + (wn * 16 + lrow) * 64; \
    _Pragma("unroll") for (int ks_ = 0; ks_ < 2; ++ks_) \
        bb[ks_] = *(const short8*)&p_[((ks_ * 4 + quad) ^ rx) << 3]; \
    } while (0)

#define MFMA_PH2(c) do { \
    __builtin_amdgcn_s_setprio(1); \
    _Pragma("unroll") for (int ks_ = 0; ks_ < 2; ++ks_) \
        _Pragma("unroll") for (int fr_ = 0; fr_ < 4; ++fr_) \
            acc[fr_][c] = mfma16(a[fr_][ks_], bb[ks_], acc[fr_][c]); \
    __builtin_amdgcn_s_setprio(0); \
    } while (0)

__global__ __launch_bounds__(512, 2) void out_gemm2ph(
    const short* __restrict__ AV, const short* __restrict__ Wo,
    const short* __restrict__ bo, float* __restrict__ out)
{
    __shared__ short As2[2 * 2 * 4096];   // 32 KiB
    __shared__ short Bs2[2 * 2 * 4096];   // 32 KiB
    const int tid  = threadIdx.x;
    const int wid  = tid >> 6;
    const int lane = tid & 63;
    const int wm   = wid >> 2;
    const int wn   = wid & 3;
    const int lrow = lane & 15;
    const int quad = lane >> 4;
    const int rx   = lrow & 7;
    const int bid  = blockIdx.x + blockIdx.y * 32;
    const int xcd  = bid & 7, gg = bid >> 3;
    const int mi   = (xcd & 3) * 8 + (gg & 7);       // 0..31
    const int ni   = (xcd >> 2) * 4 + (gg >> 3);     // 0..7
    const int m0   = mi * 128, n0 = ni * 128;
    const short* Asrc = AV + (size_t)m0 * 1024;
    const short* Bsrc = Wo + (size_t)n0 * 1024;

    floatx4 acc[4][2];
#pragma unroll
    for (int r = 0; r < 4; ++r)
#pragma unroll
        for (int c = 0; c < 2; ++c) acc[r][c] = (floatx4){0.f, 0.f, 0.f, 0.f};

    short8 a[4][2], bb[2];

    STG4(0, 0);
    VM0; BARR;

#pragma unroll 2
    for (int t = 0; t < 16; ++t) {
        const int cur = t & 1;
        if (t < 15) STG4(cur ^ 1, t + 1);
        RD_A2(cur);
        RD_B2(cur, 0); MFMA_PH2(0);
        RD_B2(cur, 1); MFMA_PH2(1);
        VM0; BARR;
    }

#pragma unroll
    for (int fc = 0; fc < 2; ++fc) {
        int col = n0 + fc * 64 + wn * 16 + lrow;
        float bv = bf2f((uint16_t)bo[col]);
#pragma unroll
        for (int fr = 0; fr < 4; ++fr) {
#pragma unroll
            for (int g = 0; g < 4; ++g) {
                int m = m0 + wm * 64 + fr * 16 + quad * 4 + g;
                out[(size_t)m * 1024 + col] = acc[fr][fc][g] + bv;
            }
        }
    }
}

// ---------- flash attention v2 (R7-exact structure) + cvt_pk P-store ----------
// R9: REVERT of R8's 64-row restructure (occupancy up but time 49->90us:
// 16-row tiles halved B-reuse, Q-direct latency sat on the jt critical path).
// Back to: 128-row blocks, 8 waves = 4 rg x 2 cg, K/Q/V dbuf LDS, grid 512.
// ONE change vs R7: P-store conversion uses v_cvt_pk_bf16_f32 (2 vals/instr,
// HW RNE) instead of 16 scalar f2bf — cuts ~55 VALU instr/wave/jt of ~160
// (VALUBusy was 47%, the largest pipe component).
#define PSTR 72   // Ps row stride (shorts): 16B-aligned
__global__ __launch_bounds__(512, 4) void attn_kernel(
    const short* __restrict__ Q, const short* __restrict__ K,
    const short* __restrict__ Vt, const short* __restrict__ ErT,
    short* __restrict__ AV)
{
    __shared__ short smem[33792];            // 66 KiB, flat
    short* Ks  = smem;                       // [2][4096]
    short* Qks = smem + 8192;                // [2][4096]
    short* Vs  = smem + 16384;               // [2][4096]
    short* Ps  = smem + 24576;               // [128*PSTR]
    float* oaccS = (float*)smem;             // [128][65] f32 end-combine scratch
    float* lrunS = ((float*)smem) + 128 * 65; // 128 f32

    const int tid  = threadIdx.x;
    const int wid  = tid >> 6;
    const int lane = tid & 63;
    const int rg   = wid >> 1;          // 0..3: row-group (32 q-rows)
    const int cg   = wid & 1;           // 0..1: col-group (32 j's)
    const int lrow = lane & 15;
    const int quad = lane >> 4;
    const int lk   = quad * 8;
    const int srow = lane >> 3;
    const int sscol = (((lane & 7) ^ (srow & 7)) << 3);
    const int rx = lrow & 7;
    const int h = blockIdx.x, b = blockIdx.y;
    const int bh = b * 16 + h;
    const int i0 = blockIdx.z * 128;
    const short* Qbh = Q  + (size_t)bh * 65536;
    const short* Kbh = K  + (size_t)bh * 65536;
    const short* Vbh = Vt + (size_t)bh * 65536;

    // Qaug A-frags: 32 rows (2 m-tiles) x full K=128 ([Q | ErT])
    short8 qa[2][4];
#pragma unroll
    for (int m = 0; m < 2; ++m) {
        int row = i0 + rg * 32 + m * 16 + lrow;
#pragma unroll
        for (int kk = 0; kk < 2; ++kk) {
            qa[m][kk]     = *(const short8*)&Qbh[(size_t)row * 64 + kk * 32 + lk];
            qa[m][kk + 2] = *(const short8*)&ErT[(size_t)row * 64 + kk * 32 + lk];
        }
    }

    float lrun[2][4];
    floatx4 oacc[2][4];
#pragma unroll
    for (int m = 0; m < 2; ++m) {
#pragma unroll
        for (int g = 0; g < 4; ++g) lrun[m][g] = 0.f;
#pragma unroll
        for (int c = 0; c < 4; ++c) oacc[m][c] = (floatx4){0.f, 0.f, 0.f, 0.f};
    }

    // prologue: stage jt=0 into buffer 0 (wave wid stages chunk wid of each)
    gll16(Kbh + (size_t)(wid * 8 + srow) * 64 + sscol,    Ks  + wid * 512 + lane * 8);
    gll16(Qbh + (size_t)(wid * 8 + srow) * 64 + sscol,    Qks + wid * 512 + lane * 8);
    gll16(Vbh + (size_t)(wid * 8 + srow) * 1024 + sscol,  Vs  + wid * 512 + lane * 8);

    const float sc2 = 1.44269504088896f / 32.0f;   // log2(e)/sqrt(c)

    for (int jt = 0; jt < 16; ++jt) {
        const int cur = jt & 1;
        __syncthreads();   // buf[cur] staged + all waves done reading it last round

        if (jt < 15) {     // prefetch jt+1 into buf[cur^1]
            int j1 = (jt + 1) * 64;
            gll16(Kbh + (size_t)(j1 + wid * 8 + srow) * 64 + sscol,    Ks  + (cur ^ 1) * 4096 + wid * 512 + lane * 8);
            gll16(Qbh + (size_t)(j1 + wid * 8 + srow) * 64 + sscol,    Qks + (cur ^ 1) * 4096 + wid * 512 + lane * 8);
            gll16(Vbh + (size_t)(wid * 8 + srow) * 1024 + j1 + sscol,  Vs  + (cur ^ 1) * 4096 + wid * 512 + lane * 8);
        }

        // S-MFMA: rows rg*32..+31 x cols (j) cg*32..+31
        floatx4 s[2][2];
#pragma unroll
        for (int m = 0; m < 2; ++m)
#pragma unroll
            for (int c = 0; c < 2; ++c) s[m][c] = (floatx4){0.f, 0.f, 0.f, 0.f};
#pragma unroll
        for (int kk = 0; kk < 4; ++kk) {
            short8 kb[2];
            const short* src = ((kk < 2) ? Ks : Qks) + cur * 4096;
            const int kl = kk & 1;
#pragma unroll
            for (int c = 0; c < 2; ++c)
                kb[c] = *(const short8*)&src[(cg * 32 + c * 16 + lrow) * 64 +
                                             (((kl * 4 + quad) ^ rx) << 3)];
#pragma unroll
            for (int m = 0; m < 2; ++m)
#pragma unroll
                for (int c = 0; c < 2; ++c)
                    s[m][c] = mfma16(qa[m][kk], kb[c], s[m][c]);
        }

        // no-max softmax: p = exp2(s*sc2); per-lane partial row sums (deferred)
#pragma unroll
        for (int m = 0; m < 2; ++m)
#pragma unroll
            for (int c = 0; c < 2; ++c)
#pragma unroll
                for (int g = 0; g < 4; ++g)
                    s[m][c][g] = exp2f(s[m][c][g] * sc2);
#pragma unroll
        for (int m = 0; m < 2; ++m)
#pragma unroll
            for (int g = 0; g < 4; ++g)
                lrun[m][g] += s[m][0][g] + s[m][1][g];

        // write P to wave-private 32x32 block of Ps — packed bf16 conversion
#pragma unroll
        for (int m = 0; m < 2; ++m)
#pragma unroll
            for (int c = 0; c < 2; ++c) {
                uint32_t u0 = pk2bf(s[m][c][0], s[m][c][1]);
                uint32_t u1 = pk2bf(s[m][c][2], s[m][c][3]);
                short* base = &Ps[(rg * 32 + m * 16 + quad * 4) * PSTR +
                                  cg * 32 + c * 16 + lrow];
                base[0]        = (short)(u0 & 0xffffu);
                base[PSTR]     = (short)(u0 >> 16);
                base[2 * PSTR] = (short)(u1 & 0xffffu);
                base[3 * PSTR] = (short)(u1 >> 16);
            }
        __asm__ __volatile__("" ::: "memory");

        // PV-MFMA: k = wave's 32 j's (single K=32 step)
        {
            short8 pa[2], vb[4];
#pragma unroll
            for (int m = 0; m < 2; ++m)
                pa[m] = *(const short8*)&Ps[(rg * 32 + m * 16 + lrow) * PSTR + cg * 32 + lk];
#pragma unroll
            for (int c = 0; c < 4; ++c)
                vb[c] = *(const short8*)&Vs[cur * 4096 + (c * 16 + lrow) * 64 +
                                            (((cg * 4 + quad) ^ rx) << 3)];
#pragma unroll
            for (int m = 0; m < 2; ++m)
#pragma unroll
                for (int c = 0; c < 4; ++c)
                    oacc[m][c] = mfma16(pa[m], vb[c], oacc[m][c]);
        }
    }

    // ---- end-combine across the 2 col-groups ----
#pragma unroll
    for (int m = 0; m < 2; ++m)
#pragma unroll
        for (int g = 0; g < 4; ++g) {
            float r = lrun[m][g];
#pragma unroll
            for (int d = 1; d < 16; d <<= 1) r += __shfl_xor(r, d, 64);
            lrun[m][g] = r;
        }

    __syncthreads();   // all LDS reads of the jt loop complete
    if (cg == 0) {
#pragma unroll
        for (int m = 0; m < 2; ++m) {
#pragma unroll
            for (int c = 0; c < 4; ++c)
#pragma unroll
                for (int g = 0; g < 4; ++g)
                    oaccS[(rg * 32 + m * 16 + quad * 4 + g) * 65 + c * 16 + lrow] =
                        oacc[m][c][g];
            if (lrow == 0)
#pragma unroll
                for (int g = 0; g < 4; ++g)
                    lrunS[rg * 32 + m * 16 + quad * 4 + g] = lrun[m][g];
        }
    }
    __syncthreads();
    if (cg == 1) {
#pragma unroll
        for (int m = 0; m < 2; ++m)
#pragma unroll
            for (int g = 0; g < 4; ++g) {
                int row = rg * 32 + m * 16 + quad * 4 + g;
                float lt = lrun[m][g] + lrunS[row];
#pragma unroll
                for (int c = 0; c < 4; ++c) {
                    float tot = oacc[m][c][g] + oaccS[row * 65 + c * 16 + lrow];
                    AV[((size_t)b * 1024 + i0 + row) * 1024 + h * 64 + c * 16 + lrow] =
                        (short)f2bf(tot / lt);
                }
            }
    }
}

// ---------- launcher ----------
extern "C" void kernel_launch(void* const* d_in, const int* in_sizes, int n_in,
                              void* d_out, int out_size, void* d_ws, size_t ws_size,
                              hipStream_t stream) {
    const float* x  = (const float*)d_in[0];
    const float* Wq = (const float*)d_in[1];
    const float* bq = (const float*)d_in[2];
    const float* Wk = (const float*)d_in[3];
    const float* bk = (const float*)d_in[4];
    const float* Wv = (const float*)d_in[5];
    const float* bv = (const float*)d_in[6];
    const float* Wo = (const float*)d_in[7];
    const float* bo = (const float*)d_in[8];
    const float* er = (const float*)d_in[9];
    float* out = (float*)d_out;

    const size_t M1 = 1u << 20;
    short* ws   = (short*)d_ws;
    short* xb   = (short*)d_out;      // bf16 x in d_out's first 8MB; dead before out_gemm
    short* Qb   = ws;                 // 4M  [b,h,w,d]
    short* Kb   = ws + 4 * M1;        // 4M  [b,h,w,d]
    short* Vb   = ws + 8 * M1;        // 4M  [b,h,d,w]
    short* AVb  = ws + 12 * M1;       // 4M  [b,w,c]
    short* Wb   = ws + 16 * M1;       // 4M  (Wq|Wk|Wv|Wo bf16, contiguous)
    short* ball = ws + 20 * M1;       // 4x1024 (bq,bk,bv,bo)
    short* ErT  = ws + 20 * M1 + 4096; // 65536 [w,d]

    static bool attr_done = false;
    if (!attr_done) {
        hipFuncSetAttribute((const void*)qkv_gemm2ph,
                            hipFuncAttributeMaxDynamicSharedMemorySize, 114688);
        attr_done = true;
    }

    hipLaunchKernelGGL(conv_all, dim3(8464), dim3(256), 0, stream,
                       x, Wq, Wk, Wv, Wo, bq, bk, bv, bo, er, xb, Wb, ball, ErT);
    hipLaunchKernelGGL(qkv_gemm2ph, dim3(256), dim3(512), 114688, stream,
                       xb, Wb, ball, Qb, Kb, Vb);
    hipLaunchKernelGGL(attn_kernel, dim3(16, 4, 8), dim3(512), 0, stream,
                       Qb, Kb, Vb, ErT, AVb);
    hipLaunchKernelGGL(out_gemm2ph, dim3(32, 8), dim3(512), 0, stream,
                       AVb, Wb + 3 * M1, ball + 3072, out);
}